// Round 17
// baseline (1103.936 us; speedup 1.0000x reference)
//
#include <hip/hip_runtime.h>
#include <hip/hip_bf16.h>
#include <hip/hip_cooperative_groups.h>

namespace cg = cooperative_groups;

// ---------------------------------------------------------------------------
// GAT (2 layers) + mean pool + MLP head -- SINGLE cooperative mega-kernel.
// R15->R16: the 9-dispatch chain cost ~8us/launch in serial gaps (~70us of
// 168us total). All phases folded into one hipLaunchCooperativeKernel with
// grid.sync() between them; phase bodies are the R15 kernels verbatim,
// converted to grid-stride (returns -> guards; 64-thread GEMM blocks ->
// wave-level virtual indices). __launch_bounds__(256,4) + occupancy-clamped
// grid guarantees co-residency (no barrier deadlock).
// ---------------------------------------------------------------------------

typedef unsigned short u16;
typedef unsigned int u32;
typedef __attribute__((ext_vector_type(8))) short bf16x8;
typedef __attribute__((ext_vector_type(4))) float f32x4;

#define LRELU(v) ((v) > 0.0f ? (v) : 0.2f * (v))
#define ELU(v)   ((v) > 0.0f ? (v) : expm1f(v))

__device__ __forceinline__ u16 f2bf(float f) {
    union { float f; u32 u; } c; c.f = f;
    u32 u = c.u;
    u32 r = (u + 0x7fffu + ((u >> 16) & 1u)) >> 16;
    return (u16)r;
}
__device__ __forceinline__ float bf2f(u16 h) {
    return __uint_as_float(((u32)h) << 16);
}

__device__ __forceinline__ int bsum_pref(const int* __restrict__ bsum,
                                         int nb, int b, int lane) {
    int v = (lane < nb) ? bsum[lane] : 0;
#pragma unroll
    for (int off = 1; off < 32; off <<= 1) {
        int u = __shfl_up(v, off);
        if (lane >= off) v += u;
    }
    int p = __shfl(v, (b > 0) ? (b - 1) : 0);
    return (b > 0) ? p : 0;
}

__device__ __forceinline__ int lower_bound_i(const int* arr, int n, int key) {
    int lo = 0, hi = n;
    while (lo < hi) {
        int mid = (lo + hi) >> 1;
        if (arr[mid] < key) lo = mid + 1; else hi = mid;
    }
    return lo;
}

struct MegaParams {
    const float* x; const int* srcA; const int* dstA; const int* batch;
    const float* W1; const float* a_s1; const float* a_d1; const float* b1;
    const float* W2; const float* a_s2; const float* a_d2; const float* b2;
    const float* fcw1; const float* fcb1; const float* fcw2; const float* fcb2;
    float* out;
    u16* xbf; u16* xaggF; u16* out1F; u16* h2bf; float* out2;
    u16* W1f; u16* W2f; float* Wa;
    float* alS1; float* alD1; float* alS2; float* alD2; float* wE1;
    int* deg; int* fill; int* offs; int* bsum; int* sCSR;
    int Nn, E, Et, NG, NB, NBx, EB, ZB, ngroups, ngp;
};

__global__ __launch_bounds__(256, 4) void mega_kernel(MegaParams P) {
    cg::grid_group grid = cg::this_grid();
    const int nb = gridDim.x;
    const int tid = threadIdx.x;
    const int lane = tid & 63;
    const int wv = tid >> 6;

    __shared__ int sh_scan[256];
    __shared__ int shp[2];
    __shared__ float psum[4][64];
    __shared__ float pbuf[64];
    __shared__ float hidb[32];

    // ================= phase 1: W frag cast + Wa fold + zero deg/fill ======
    {
        const int P1 = 388 + P.ZB;
        for (int b = blockIdx.x; b < P1; b += nb) {
            if (b < 384) {
                int idx = b * 256 + tid;
                if (idx < 65536) {
                    int fid = idx >> 9, l = (idx >> 3) & 63, j = idx & 7;
                    int head = fid >> 5, cb = (fid >> 2) & 7, s = fid & 3;
                    int col = head * 128 + cb * 16 + (l & 15);
                    int k = s * 32 + 16 * (j >> 2) + 4 * (l >> 4) + (j & 3);
                    P.W1f[idx] = f2bf(P.W1[(size_t)k * 512 + col]);
                } else {
                    int i2 = idx - 65536;
                    int fid = i2 >> 9, l = (i2 >> 3) & 63, j = i2 & 7;
                    int c2 = fid >> 4, s = fid & 15;
                    int col = c2 * 16 + (l & 15);
                    int k = s * 32 + 16 * (j >> 2) + 4 * (l >> 4) + (j & 3);
                    P.W2f[i2] = f2bf(P.W2[(size_t)k * 64 + col]);
                }
            } else if (b < 388) {
                int idx = (b - 384) * 256 + tid;     // 0..1023
                int k = idx >> 3, j = idx & 7, h = j & 3;
                const float* a = (j < 4) ? (P.a_s1 + h * 128) : (P.a_d1 + h * 128);
                const float* wrow = P.W1 + (size_t)k * 512 + h * 128;
                float s = 0.f;
#pragma unroll 8
                for (int o = 0; o < 128; ++o) s += wrow[o] * a[o];
                P.Wa[k * 8 + j] = s;
            } else {
                int i = (b - 388) * 1024 + tid * 4;
                if (i < 2 * P.Nn) *(int4*)(P.deg + i) = make_int4(0, 0, 0, 0);
            }
        }
    }
    __threadfence();
    grid.sync();

    // ================= phase 2: prep_x (xbf + al1) + degree count ==========
    {
        const int P2 = P.NBx + P.EB;
        for (int b = blockIdx.x; b < P2; b += nb) {
            if (b >= P.NBx) {
                int e = (b - P.NBx) * 256 + tid;
                if (e < P.Et) {
                    int d = (e < P.E) ? P.dstA[e] : (e - P.E);
                    atomicAdd(&P.deg[d], 1);
                }
            } else {
                int n = b * 4 + wv;
                if (n < P.Nn) {
                    int f0 = lane * 2;
                    float4 s0v = *(const float4*)(P.Wa + f0 * 8);
                    float4 d0v = *(const float4*)(P.Wa + f0 * 8 + 4);
                    float4 s1v = *(const float4*)(P.Wa + (f0 + 1) * 8);
                    float4 d1v = *(const float4*)(P.Wa + (f0 + 1) * 8 + 4);
                    float2 xv = *(const float2*)(P.x + (size_t)n * 128 + f0);
                    *(u32*)(P.xbf + (size_t)n * 128 + f0) =
                        (u32)f2bf(xv.x) | ((u32)f2bf(xv.y) << 16);
                    float r0 = xv.x * s0v.x + xv.y * s1v.x;
                    float r1 = xv.x * s0v.y + xv.y * s1v.y;
                    float r2 = xv.x * s0v.z + xv.y * s1v.z;
                    float r3 = xv.x * s0v.w + xv.y * s1v.w;
                    float r4 = xv.x * d0v.x + xv.y * d1v.x;
                    float r5 = xv.x * d0v.y + xv.y * d1v.y;
                    float r6 = xv.x * d0v.z + xv.y * d1v.z;
                    float r7 = xv.x * d0v.w + xv.y * d1v.w;
#pragma unroll
                    for (int off = 32; off; off >>= 1) {
                        r0 += __shfl_down(r0, off); r1 += __shfl_down(r1, off);
                        r2 += __shfl_down(r2, off); r3 += __shfl_down(r3, off);
                        r4 += __shfl_down(r4, off); r5 += __shfl_down(r5, off);
                        r6 += __shfl_down(r6, off); r7 += __shfl_down(r7, off);
                    }
                    if (lane == 0) {
                        *(float4*)(P.alS1 + (size_t)n * 4) = make_float4(r0, r1, r2, r3);
                        *(float4*)(P.alD1 + (size_t)n * 4) = make_float4(r4, r5, r6, r7);
                    }
                }
            }
        }
    }
    __threadfence();
    grid.sync();

    // ================= phase 3: scanA (block-partial exclusive + bsum) =====
    {
        for (int b = blockIdx.x; b < P.NB; b += nb) {
            int base = b * 2048 + tid * 8;
            int v[8]; int s = 0;
#pragma unroll
            for (int j = 0; j < 8; ++j) {
                int i = base + j;
                v[j] = (i < P.Nn) ? P.deg[i] : 0;
                s += v[j];
            }
            sh_scan[tid] = s;
            __syncthreads();
            for (int off = 1; off < 256; off <<= 1) {
                int u = (tid >= off) ? sh_scan[tid - off] : 0;
                __syncthreads();
                sh_scan[tid] += u;
                __syncthreads();
            }
            int run = sh_scan[tid] - s;
            if (tid == 255) P.bsum[b] = sh_scan[255];
#pragma unroll
            for (int j = 0; j < 8; ++j) {
                int i = base + j;
                if (i < P.Nn) P.offs[i] = run;
                run += v[j];
            }
            __syncthreads();
        }
    }
    __threadfence();
    grid.sync();

    // ================= phase 4: scatter + layer-1 edge weights =============
    {
        for (int b = blockIdx.x; b < P.EB; b += nb) {
            int e = b * 256 + tid;
            bool live = (e < P.Et);
            int s = 0, d = 0;
            if (live) {
                s = (e < P.E) ? P.srcA[e] : (e - P.E);
                d = (e < P.E) ? P.dstA[e] : (e - P.E);
            }
            int pref = bsum_pref(P.bsum, P.NB, d >> 11, lane);
            if (live) {
                int pos = P.offs[d] + pref + atomicAdd(&P.fill[d], 1);
                P.sCSR[pos] = s;
                float4 as = *(const float4*)(P.alS1 + (size_t)s * 4);
                float4 ad = *(const float4*)(P.alD1 + (size_t)d * 4);
                float4 w;
                float t;
                t = as.x + ad.x; w.x = expf(LRELU(t));
                t = as.y + ad.y; w.y = expf(LRELU(t));
                t = as.z + ad.z; w.z = expf(LRELU(t));
                t = as.w + ad.w; w.w = expf(LRELU(t));
                *(float4*)(P.wE1 + (size_t)pos * 4) = w;
            }
        }
    }
    __threadfence();
    grid.sync();

    // ================= phase 5: aggx -> xaggF (B-frag order) ===============
    {
        const int P5 = (P.Nn + 3) / 4;
        for (int b = blockIdx.x; b < P5; b += nb) {
            int n = b * 4 + wv;
            int pref = bsum_pref(P.bsum, P.NB, (n < P.Nn ? n : 0) >> 11, lane);
            if (n < P.Nn) {
                int half = lane >> 5;
                int fl = (lane & 31) * 4;
                float a0[4] = {0.f, 0.f, 0.f, 0.f};
                float a1[4] = {0.f, 0.f, 0.f, 0.f};
                float a2[4] = {0.f, 0.f, 0.f, 0.f};
                float a3[4] = {0.f, 0.f, 0.f, 0.f};
                float ws0 = 0.f, ws1 = 0.f, ws2 = 0.f, ws3 = 0.f;
                int s0 = P.offs[n] + pref;
                int s1 = s0 + P.deg[n];
                int i = s0 + half;
                for (; i + 6 < s1; i += 8) {
                    int sn[4]; float4 w[4]; ushort4 u[4];
#pragma unroll
                    for (int j = 0; j < 4; ++j) {
                        int idx = i + 2 * j;
                        sn[j] = P.sCSR[idx];
                        w[j] = *(const float4*)(P.wE1 + (size_t)idx * 4);
                    }
#pragma unroll
                    for (int j = 0; j < 4; ++j)
                        u[j] = *(const ushort4*)(P.xbf + (size_t)sn[j] * 128 + fl);
#pragma unroll
                    for (int j = 0; j < 4; ++j) {
                        float xv[4] = {bf2f(u[j].x), bf2f(u[j].y), bf2f(u[j].z), bf2f(u[j].w)};
#pragma unroll
                        for (int q = 0; q < 4; ++q) {
                            a0[q] += w[j].x * xv[q];
                            a1[q] += w[j].y * xv[q];
                            a2[q] += w[j].z * xv[q];
                            a3[q] += w[j].w * xv[q];
                        }
                        ws0 += w[j].x; ws1 += w[j].y; ws2 += w[j].z; ws3 += w[j].w;
                    }
                }
                for (; i < s1; i += 2) {
                    int sn = P.sCSR[i];
                    float4 w = *(const float4*)(P.wE1 + (size_t)i * 4);
                    ushort4 u = *(const ushort4*)(P.xbf + (size_t)sn * 128 + fl);
                    float xv[4] = {bf2f(u.x), bf2f(u.y), bf2f(u.z), bf2f(u.w)};
#pragma unroll
                    for (int q = 0; q < 4; ++q) {
                        a0[q] += w.x * xv[q];
                        a1[q] += w.y * xv[q];
                        a2[q] += w.z * xv[q];
                        a3[q] += w.w * xv[q];
                    }
                    ws0 += w.x; ws1 += w.y; ws2 += w.z; ws3 += w.w;
                }
#pragma unroll
                for (int q = 0; q < 4; ++q) {
                    a0[q] += __shfl_xor(a0[q], 32);
                    a1[q] += __shfl_xor(a1[q], 32);
                    a2[q] += __shfl_xor(a2[q], 32);
                    a3[q] += __shfl_xor(a3[q], 32);
                }
                ws0 += __shfl_xor(ws0, 32); ws1 += __shfl_xor(ws1, 32);
                ws2 += __shfl_xor(ws2, 32); ws3 += __shfl_xor(ws3, 32);
                if (half == 0) {
                    float i0 = 1.f / ws0, i1 = 1.f / ws1, i2 = 1.f / ws2, i3 = 1.f / ws3;
                    int group = n >> 4, lrow = n & 15;
                    int sl = fl >> 5;
                    int kg = (fl >> 2) & 3;
                    int j0 = ((fl >> 4) & 1) * 4;
                    size_t base = ((size_t)group * 16 + sl) * 512 +
                                  (size_t)(kg * 16 + lrow) * 8 + j0;
                    ushort4 o;
                    o.x = f2bf(a0[0] * i0); o.y = f2bf(a0[1] * i0);
                    o.z = f2bf(a0[2] * i0); o.w = f2bf(a0[3] * i0);
                    *(ushort4*)(P.xaggF + base + 0 * 2048) = o;
                    o.x = f2bf(a1[0] * i1); o.y = f2bf(a1[1] * i1);
                    o.z = f2bf(a1[2] * i1); o.w = f2bf(a1[3] * i1);
                    *(ushort4*)(P.xaggF + base + 1 * 2048) = o;
                    o.x = f2bf(a2[0] * i2); o.y = f2bf(a2[1] * i2);
                    o.z = f2bf(a2[2] * i2); o.w = f2bf(a2[3] * i2);
                    *(ushort4*)(P.xaggF + base + 2 * 2048) = o;
                    o.x = f2bf(a3[0] * i3); o.y = f2bf(a3[1] * i3);
                    o.z = f2bf(a3[2] * i3); o.w = f2bf(a3[3] * i3);
                    *(ushort4*)(P.xaggF + base + 3 * 2048) = o;
                }
            }
        }
    }
    __threadfence();
    grid.sync();

    // ================= phase 6: gemm1 (wave-level virtual blocks) ==========
    {
        const int NG2 = P.ngp / 2;
        for (int v = blockIdx.x * 4 + wv; v < NG2 * 4; v += nb * 4) {
            int head = v / NG2;
            int bx = v - head * NG2;
            int g0 = bx * 2;
            int kg = lane >> 4;
            bf16x8 xf[2][4];
#pragma unroll
            for (int g = 0; g < 2; ++g) {
                const u16* p = P.xaggF + ((size_t)(g0 + g) * 16 + head * 4) * 512 + lane * 8;
#pragma unroll
                for (int s = 0; s < 4; ++s) xf[g][s] = *(const bf16x8*)(p + s * 512);
            }
            const u16* wbase = P.W1f + (size_t)head * 32 * 512 + lane * 8;
#pragma unroll
            for (int cbp = 0; cbp < 4; ++cbp) {
                bf16x8 op0, op1;
#pragma unroll
                for (int par = 0; par < 2; ++par) {
                    int cb = cbp * 2 + par;
                    bf16x8 wf[4];
#pragma unroll
                    for (int s = 0; s < 4; ++s)
                        wf[s] = *(const bf16x8*)(wbase + (size_t)(cb * 4 + s) * 512);
                    float4 bias = *(const float4*)(P.b1 + head * 128 + cb * 16 + kg * 4);
#pragma unroll
                    for (int g = 0; g < 2; ++g) {
                        f32x4 acc = {0.f, 0.f, 0.f, 0.f};
#pragma unroll
                        for (int s = 0; s < 4; ++s)
                            acc = __builtin_amdgcn_mfma_f32_16x16x32_bf16(wf[s], xf[g][s],
                                                                          acc, 0, 0, 0);
                        float v0 = ELU(acc[0] + bias.x);
                        float v1 = ELU(acc[1] + bias.y);
                        float v2 = ELU(acc[2] + bias.z);
                        float v3 = ELU(acc[3] + bias.w);
                        bf16x8& op = g ? op1 : op0;
                        if (par == 0) {
                            op[0] = (short)f2bf(v0); op[1] = (short)f2bf(v1);
                            op[2] = (short)f2bf(v2); op[3] = (short)f2bf(v3);
                        } else {
                            op[4] = (short)f2bf(v0); op[5] = (short)f2bf(v1);
                            op[6] = (short)f2bf(v2); op[7] = (short)f2bf(v3);
                        }
                    }
                }
#pragma unroll
                for (int g = 0; g < 2; ++g) {
                    u16* op = P.out1F + ((size_t)(g0 + g) * 16 + head * 4 + cbp) * 512 + lane * 8;
                    *(bf16x8*)op = g ? op1 : op0;
                }
            }
        }
    }
    __threadfence();
    grid.sync();

    // ================= phase 7: gemm2 + fused al2 ==========================
    {
        for (int v = blockIdx.x * 4 + wv; v < P.ngroups; v += nb * 4) {
            int lrow = lane & 15, kg = lane >> 4;
            int node = v * 16 + lrow;
            const u16* xp = P.out1F + (size_t)v * 16 * 512 + lane * 8;
            bf16x8 xf[16];
#pragma unroll
            for (int s = 0; s < 16; ++s) xf[s] = *(const bf16x8*)(xp + s * 512);
            const u16* wp = P.W2f + lane * 8;
            float ps = 0.f, pd = 0.f;
#pragma unroll
            for (int c2 = 0; c2 < 4; ++c2) {
                int c0 = c2 * 16;
                f32x4 acc = {0.f, 0.f, 0.f, 0.f};
#pragma unroll
                for (int s = 0; s < 16; ++s) {
                    bf16x8 wf = *(const bf16x8*)(wp + (size_t)(c2 * 16 + s) * 512);
                    acc = __builtin_amdgcn_mfma_f32_16x16x32_bf16(wf, xf[s], acc, 0, 0, 0);
                }
                float4 as = *(const float4*)(P.a_s2 + c0 + kg * 4);
                float4 ad = *(const float4*)(P.a_d2 + c0 + kg * 4);
                ps += acc[0] * as.x + acc[1] * as.y + acc[2] * as.z + acc[3] * as.w;
                pd += acc[0] * ad.x + acc[1] * ad.y + acc[2] * ad.z + acc[3] * ad.w;
                if (node < P.Nn) {
                    ushort4 o;
                    o.x = f2bf(acc[0]); o.y = f2bf(acc[1]);
                    o.z = f2bf(acc[2]); o.w = f2bf(acc[3]);
                    *(ushort4*)(P.h2bf + (size_t)node * 64 + c0 + kg * 4) = o;
                }
            }
            ps += __shfl_xor(ps, 16); ps += __shfl_xor(ps, 32);
            pd += __shfl_xor(pd, 16); pd += __shfl_xor(pd, 32);
            if (kg == 0 && node < P.Nn) { P.alS2[node] = ps; P.alD2[node] = pd; }
        }
    }
    __threadfence();
    grid.sync();

    // ================= phase 8: agg2 (weights inline) ======================
    {
        const int P5 = (P.Nn + 3) / 4;
        for (int b = blockIdx.x; b < P5; b += nb) {
            int n = b * 4 + wv;
            int pref = bsum_pref(P.bsum, P.NB, (n < P.Nn ? n : 0) >> 11, lane);
            if (n < P.Nn) {
                int half = lane >> 5;
                int fl = (lane & 31) * 2;
                float ad = P.alD2[n];
                float ax = 0.f, ay = 0.f, ws = 0.f;
                int s0 = P.offs[n] + pref;
                int s1 = s0 + P.deg[n];
                int i = s0 + half;
                for (; i + 6 < s1; i += 8) {
                    int sn[4]; float als[4]; u32 u[4];
#pragma unroll
                    for (int j = 0; j < 4; ++j) sn[j] = P.sCSR[i + 2 * j];
#pragma unroll
                    for (int j = 0; j < 4; ++j) {
                        als[j] = P.alS2[sn[j]];
                        u[j] = *(const u32*)(P.h2bf + (size_t)sn[j] * 64 + fl);
                    }
#pragma unroll
                    for (int j = 0; j < 4; ++j) {
                        float t = als[j] + ad;
                        float w = expf(LRELU(t));
                        ax += w * __uint_as_float(u[j] << 16);
                        ay += w * __uint_as_float(u[j] & 0xffff0000u);
                        ws += w;
                    }
                }
                for (; i < s1; i += 2) {
                    int sn = P.sCSR[i];
                    float t = P.alS2[sn] + ad;
                    float w = expf(LRELU(t));
                    u32 u = *(const u32*)(P.h2bf + (size_t)sn * 64 + fl);
                    ax += w * __uint_as_float(u << 16);
                    ay += w * __uint_as_float(u & 0xffff0000u);
                    ws += w;
                }
                ax += __shfl_xor(ax, 32);
                ay += __shfl_xor(ay, 32);
                ws += __shfl_xor(ws, 32);
                if (half == 0) {
                    float inv = 1.f / ws;
                    float2 o;
                    float v0 = ax * inv + P.b2[fl];
                    float v1 = ay * inv + P.b2[fl + 1];
                    o.x = ELU(v0);
                    o.y = ELU(v1);
                    *(float2*)(P.out2 + (size_t)n * 64 + fl) = o;
                }
            }
        }
    }
    __threadfence();
    grid.sync();

    // ================= phase 9: pool + MLP head ============================
    {
        for (int g = blockIdx.x; g < P.NG; g += nb) {
            int w = wv, t = lane;
            if (tid == 0) shp[0] = lower_bound_i(P.batch, P.Nn, g);
            if (tid == 1) shp[1] = lower_bound_i(P.batch, P.Nn, g + 1);
            __syncthreads();
            int s0 = shp[0], s1 = shp[1];
            float sum = 0.f;
            for (int i = s0 + w; i < s1; i += 4) sum += P.out2[(size_t)i * 64 + t];
            psum[w][t] = sum;
            __syncthreads();
            if (w == 0) {
                float tot = psum[0][t] + psum[1][t] + psum[2][t] + psum[3][t];
                float cnt = (float)((s1 - s0) > 1 ? (s1 - s0) : 1);
                pbuf[t] = tot / cnt;
            }
            __syncthreads();
            if (tid < 32) {
                float a = P.fcb1[tid];
#pragma unroll
                for (int k = 0; k < 64; ++k) a += pbuf[k] * P.fcw1[k * 32 + tid];
                hidb[tid] = a > 0.f ? a : 0.f;
            }
            __syncthreads();
            if (tid == 0) {
                float a = P.fcb2[0];
#pragma unroll
                for (int j = 0; j < 32; ++j) a += hidb[j] * P.fcw2[j];
                P.out[g] = 1.0f / (1.0f + expf(-a));
            }
            __syncthreads();
        }
    }
}

// ---------------------------------------------------------------------------
extern "C" void kernel_launch(void* const* d_in, const int* in_sizes, int n_in,
                              void* d_out, int out_size, void* d_ws, size_t ws_size,
                              hipStream_t stream) {
    const float* x      = (const float*)d_in[0];
    const int*   ei     = (const int*)d_in[1];
    const int*   batch  = (const int*)d_in[2];
    const float* W1     = (const float*)d_in[3];
    const float* a_src1 = (const float*)d_in[4];
    const float* a_dst1 = (const float*)d_in[5];
    const float* b1     = (const float*)d_in[6];
    const float* W2     = (const float*)d_in[7];
    const float* a_src2 = (const float*)d_in[8];
    const float* a_dst2 = (const float*)d_in[9];
    const float* b2     = (const float*)d_in[10];
    const float* fcw1   = (const float*)d_in[11];
    const float* fcb1   = (const float*)d_in[12];
    const float* fcw2   = (const float*)d_in[13];
    const float* fcb2   = (const float*)d_in[14];
    float* out = (float*)d_out;

    const int Nn = in_sizes[0] / 128;   // 25000
    const int E  = in_sizes[1] / 2;     // 400000
    const int Et = E + Nn;
    const int NG = out_size;            // 512

    const int ngroups = (Nn + 15) / 16;          // 1563
    const int ngp = (ngroups + 1) & ~1;          // padded even

    char* base = (char*)d_ws;
    size_t off = 0;
    auto alloc = [&](size_t bytes) -> void* {
        void* p = base + off;
        off += (bytes + 255) & ~(size_t)255;
        return p;
    };
    u16*   xbf    = (u16*)alloc((size_t)Nn * 128 * 2);
    u16*   xaggF  = (u16*)alloc((size_t)ngp * 16 * 512 * 2);   // B-frag order
    u16*   out1F  = (u16*)alloc((size_t)ngp * 16 * 512 * 2);   // B-frag order
    u16*   h2bf   = (u16*)alloc((size_t)Nn * 64 * 2);
    float* out2   = (float*)alloc((size_t)Nn * 64 * 4);
    u16*   W1f    = (u16*)alloc(65536 * 2);
    u16*   W2f    = (u16*)alloc(32768 * 2);
    float* Wa     = (float*)alloc(128 * 8 * 4);
    float* alS1   = (float*)alloc((size_t)Nn * 4 * 4);
    float* alD1   = (float*)alloc((size_t)Nn * 4 * 4);
    float* alS2   = (float*)alloc((size_t)Nn * 4);
    float* alD2   = (float*)alloc((size_t)Nn * 4);
    float* wE1    = (float*)alloc((size_t)Et * 4 * 4);
    int*   deg    = (int*)alloc((size_t)2 * Nn * 4);   // deg + fill contiguous
    int*   fill   = deg + Nn;
    int*   offs   = (int*)alloc((size_t)(Nn + 1) * 4);
    int*   bsum   = (int*)alloc(64 * 4);
    int*   sCSR   = (int*)alloc((size_t)Et * 4);
    (void)ws_size; (void)n_in;

    MegaParams P;
    P.x = x; P.srcA = ei; P.dstA = ei + E; P.batch = batch;
    P.W1 = W1; P.a_s1 = a_src1; P.a_d1 = a_dst1; P.b1 = b1;
    P.W2 = W2; P.a_s2 = a_src2; P.a_d2 = a_dst2; P.b2 = b2;
    P.fcw1 = fcw1; P.fcb1 = fcb1; P.fcw2 = fcw2; P.fcb2 = fcb2;
    P.out = out;
    P.xbf = xbf; P.xaggF = xaggF; P.out1F = out1F; P.h2bf = h2bf; P.out2 = out2;
    P.W1f = W1f; P.W2f = W2f; P.Wa = Wa;
    P.alS1 = alS1; P.alD1 = alD1; P.alS2 = alS2; P.alD2 = alD2; P.wE1 = wE1;
    P.deg = deg; P.fill = fill; P.offs = offs; P.bsum = bsum; P.sCSR = sCSR;
    P.Nn = Nn; P.E = E; P.Et = Et; P.NG = NG;
    P.NB = (Nn + 2047) / 2048;
    P.NBx = (Nn + 3) / 4;
    P.EB = (Et + 255) / 256;
    P.ZB = (2 * Nn + 1023) / 1024;
    P.ngroups = ngroups; P.ngp = ngp;

    // co-residency-safe grid size
    int dev = 0;
    hipGetDevice(&dev);
    hipDeviceProp_t prop;
    hipGetDeviceProperties(&prop, dev);
    int maxb = 0;
    hipOccupancyMaxActiveBlocksPerMultiprocessor(&maxb, (const void*)mega_kernel, 256, 0);
    if (maxb < 1) maxb = 1;
    long long g = (long long)prop.multiProcessorCount * maxb;
    if (g > 2048) g = 2048;
    if (g < 64) g = 64;

    void* args[] = { (void*)&P };
    hipLaunchCooperativeKernel((const void*)mega_kernel, dim3((unsigned)g), dim3(256),
                               args, 0, stream);
}

// Round 18
// 167.759 us; speedup vs baseline: 6.5805x; 6.5805x over previous
//
#include <hip/hip_runtime.h>
#include <hip/hip_bf16.h>

// ---------------------------------------------------------------------------
// GAT (2 layers) + mean pool + MLP head.
// R16->R17: REVERT of the cooperative mega-kernel (1104us -- grid.sync() on
// 8 non-coherent-L2 XCDs costs ~100us+/barrier, and launch_bounds(256,4)
// crippled GEMM VGPR). Back to the proven R15 9-dispatch structure (~168us):
// inline bsum-prefix CSR, fragment-native split GEMMs, half-wave-split
// aggregates, fused pool+head. This is the stable floor configuration:
// fusion fails on compiler VGPR caps (R6/R12), coop-launch on barrier cost
// (R16), micro-opts in noise (R15).
// ---------------------------------------------------------------------------

typedef unsigned short u16;
typedef unsigned int u32;
typedef __attribute__((ext_vector_type(8))) short bf16x8;
typedef __attribute__((ext_vector_type(4))) float f32x4;

#define LRELU(v) ((v) > 0.0f ? (v) : 0.2f * (v))
#define ELU(v)   ((v) > 0.0f ? (v) : expm1f(v))

__device__ __forceinline__ u16 f2bf(float f) {
    union { float f; u32 u; } c; c.f = f;
    u32 u = c.u;
    u32 r = (u + 0x7fffu + ((u >> 16) & 1u)) >> 16;
    return (u16)r;
}
__device__ __forceinline__ float bf2f(u16 h) {
    return __uint_as_float(((u32)h) << 16);
}

// wave-level prefix of bsum[0..nb): returns sum of bsum[0..b-1] (0 for b==0).
__device__ __forceinline__ int bsum_pref(const int* __restrict__ bsum,
                                         int nb, int b, int lane) {
    int v = (lane < nb) ? bsum[lane] : 0;
#pragma unroll
    for (int off = 1; off < 32; off <<= 1) {
        int u = __shfl_up(v, off);
        if (lane >= off) v += u;
    }
    int p = __shfl(v, (b > 0) ? (b - 1) : 0);
    return (b > 0) ? p : 0;
}

// ---- fused weight prep: W1f/W2f (fragment order) + Wa fold + zero deg -----
__global__ __launch_bounds__(256) void prep_w(const float* __restrict__ W1,
                                              const float* __restrict__ W2,
                                              const float* __restrict__ a_s,
                                              const float* __restrict__ a_d,
                                              u16* __restrict__ W1f,
                                              u16* __restrict__ W2f,
                                              float* __restrict__ Wa,
                                              int* __restrict__ deg, int nDeg) {
    int b = blockIdx.x;
    if (b < 384) {
        int idx = b * 256 + threadIdx.x;
        if (idx < 65536) {
            int fid = idx >> 9, l = (idx >> 3) & 63, j = idx & 7;
            int head = fid >> 5, cb = (fid >> 2) & 7, s = fid & 3;
            int col = head * 128 + cb * 16 + (l & 15);
            int k = s * 32 + 16 * (j >> 2) + 4 * (l >> 4) + (j & 3);
            W1f[idx] = f2bf(W1[(size_t)k * 512 + col]);
        } else {
            int i2 = idx - 65536;
            int fid = i2 >> 9, l = (i2 >> 3) & 63, j = i2 & 7;
            int c2 = fid >> 4, s = fid & 15;
            int col = c2 * 16 + (l & 15);
            int k = s * 32 + 16 * (j >> 2) + 4 * (l >> 4) + (j & 3);
            W2f[i2] = f2bf(W2[(size_t)k * 64 + col]);
        }
    } else if (b < 388) {
        int idx = (b - 384) * 256 + threadIdx.x;   // 0..1023
        int k = idx >> 3, j = idx & 7, h = j & 3;
        const float* a = (j < 4) ? (a_s + h * 128) : (a_d + h * 128);
        const float* wrow = W1 + (size_t)k * 512 + h * 128;
        float s = 0.f;
#pragma unroll 8
        for (int o = 0; o < 128; ++o) s += wrow[o] * a[o];
        Wa[k * 8 + j] = s;
    } else {
        int i = (b - 388) * 1024 + threadIdx.x * 4;
        if (i < nDeg) *(int4*)(deg + i) = make_int4(0, 0, 0, 0);
    }
}

// ---- prep_x: xbf = bf16(x) AND alS1/alD1 = x @ Wa AND degree count --------
__global__ __launch_bounds__(256) void prep_x(const float* __restrict__ x,
                                              const float* __restrict__ Wa,
                                              const int* __restrict__ dstA,
                                              u16* __restrict__ xbf,
                                              float* __restrict__ alS,
                                              float* __restrict__ alD,
                                              int* __restrict__ deg,
                                              int Nn, int E, int NBx) {
    int b = blockIdx.x;
    if (b >= NBx) {
        int e = (b - NBx) * 256 + threadIdx.x;
        if (e < E + Nn) {
            int d = (e < E) ? dstA[e] : (e - E);
            atomicAdd(&deg[d], 1);
        }
        return;
    }
    int lane = threadIdx.x & 63;
    int wave = threadIdx.x >> 6;
    int f0 = lane * 2;
    float4 s0v = *(const float4*)(Wa + f0 * 8);
    float4 d0v = *(const float4*)(Wa + f0 * 8 + 4);
    float4 s1v = *(const float4*)(Wa + (f0 + 1) * 8);
    float4 d1v = *(const float4*)(Wa + (f0 + 1) * 8 + 4);
    int n = b * 4 + wave;
    if (n >= Nn) return;
    float2 xv = *(const float2*)(x + (size_t)n * 128 + f0);
    *(u32*)(xbf + (size_t)n * 128 + f0) =
        (u32)f2bf(xv.x) | ((u32)f2bf(xv.y) << 16);
    float r0 = xv.x * s0v.x + xv.y * s1v.x;
    float r1 = xv.x * s0v.y + xv.y * s1v.y;
    float r2 = xv.x * s0v.z + xv.y * s1v.z;
    float r3 = xv.x * s0v.w + xv.y * s1v.w;
    float r4 = xv.x * d0v.x + xv.y * d1v.x;
    float r5 = xv.x * d0v.y + xv.y * d1v.y;
    float r6 = xv.x * d0v.z + xv.y * d1v.z;
    float r7 = xv.x * d0v.w + xv.y * d1v.w;
#pragma unroll
    for (int off = 32; off; off >>= 1) {
        r0 += __shfl_down(r0, off); r1 += __shfl_down(r1, off);
        r2 += __shfl_down(r2, off); r3 += __shfl_down(r3, off);
        r4 += __shfl_down(r4, off); r5 += __shfl_down(r5, off);
        r6 += __shfl_down(r6, off); r7 += __shfl_down(r7, off);
    }
    if (lane == 0) {
        *(float4*)(alS + (size_t)n * 4) = make_float4(r0, r1, r2, r3);
        *(float4*)(alD + (size_t)n * 4) = make_float4(r4, r5, r6, r7);
    }
}

// ---------------- CSR build ------------------------------------------------
// scanA: offs[i] = EXCLUSIVE prefix of deg within block; bsum[b] = block total.
__global__ __launch_bounds__(256) void scanA_kernel(const int* __restrict__ deg,
                                                    int* __restrict__ offs,
                                                    int* __restrict__ bsum, int n) {
    __shared__ int sh[256];
    int b = blockIdx.x, t = threadIdx.x;
    int base = b * 2048 + t * 8;
    int v[8]; int s = 0;
#pragma unroll
    for (int j = 0; j < 8; ++j) { int i = base + j; v[j] = (i < n) ? deg[i] : 0; s += v[j]; }
    sh[t] = s;
    __syncthreads();
    for (int off = 1; off < 256; off <<= 1) {
        int u = (t >= off) ? sh[t - off] : 0;
        __syncthreads();
        sh[t] += u;
        __syncthreads();
    }
    int run = sh[t] - s;                 // exclusive prefix of this chunk
    if (t == 255) bsum[b] = sh[255];
#pragma unroll
    for (int j = 0; j < 8; ++j) {
        int i = base + j;
        if (i < n) offs[i] = run;        // exclusive, block-partial
        run += v[j];
    }
}

// scatter: CSR order + layer-1 edge weights; global offset via bsum prefix
__global__ __launch_bounds__(256) void scatter_kernel(const int* __restrict__ src,
                                                      const int* __restrict__ dst,
                                                      int E, int Nn,
                                                      const int* __restrict__ offs,
                                                      const int* __restrict__ bsum,
                                                      int NB,
                                                      int* __restrict__ fill,
                                                      const float* __restrict__ alS,
                                                      const float* __restrict__ alD,
                                                      int* __restrict__ sCSR,
                                                      float* __restrict__ wE1) {
    int e = blockIdx.x * 256 + threadIdx.x;
    int lane = threadIdx.x & 63;
    bool live = (e < E + Nn);
    int s = 0, d = 0;
    if (live) {
        s = (e < E) ? src[e] : (e - E);
        d = (e < E) ? dst[e] : (e - E);
    }
    int pref = bsum_pref(bsum, NB, d >> 11, lane);   // all lanes participate
    if (!live) return;
    int pos = offs[d] + pref + atomicAdd(&fill[d], 1);
    sCSR[pos] = s;
    float4 as = *(const float4*)(alS + (size_t)s * 4);
    float4 ad = *(const float4*)(alD + (size_t)d * 4);
    float4 w;
    float t;
    t = as.x + ad.x; w.x = expf(LRELU(t));
    t = as.y + ad.y; w.y = expf(LRELU(t));
    t = as.z + ad.z; w.z = expf(LRELU(t));
    t = as.w + ad.w; w.w = expf(LRELU(t));
    *(float4*)(wE1 + (size_t)pos * 4) = w;
}

// ---- layer-1 aggregate -> xaggF (B-frag order), half-wave edge split ------
__global__ __launch_bounds__(256) void aggx_kernel(const u16* __restrict__ xbf,
                                                   const int* __restrict__ sCSR,
                                                   const int* __restrict__ offs,
                                                   const int* __restrict__ bsum,
                                                   const int* __restrict__ deg,
                                                   int NB,
                                                   const float* __restrict__ wE,
                                                   u16* __restrict__ xaggF, int Nn) {
    int n = blockIdx.x * 4 + (threadIdx.x >> 6);
    int l = threadIdx.x & 63;
    int pref = bsum_pref(bsum, NB, (n < Nn ? n : 0) >> 11, l);
    if (n >= Nn) return;
    int half = l >> 5;
    int fl = (l & 31) * 4;        // feats fl..fl+3
    float a0[4] = {0.f, 0.f, 0.f, 0.f};
    float a1[4] = {0.f, 0.f, 0.f, 0.f};
    float a2[4] = {0.f, 0.f, 0.f, 0.f};
    float a3[4] = {0.f, 0.f, 0.f, 0.f};
    float ws0 = 0.f, ws1 = 0.f, ws2 = 0.f, ws3 = 0.f;
    int s0 = offs[n] + pref;
    int s1 = s0 + deg[n];
    int i = s0 + half;
    for (; i + 6 < s1; i += 8) {
        int sn[4]; float4 w[4]; ushort4 u[4];
#pragma unroll
        for (int j = 0; j < 4; ++j) {
            int idx = i + 2 * j;
            sn[j] = sCSR[idx];
            w[j] = *(const float4*)(wE + (size_t)idx * 4);
        }
#pragma unroll
        for (int j = 0; j < 4; ++j)
            u[j] = *(const ushort4*)(xbf + (size_t)sn[j] * 128 + fl);
#pragma unroll
        for (int j = 0; j < 4; ++j) {
            float xv[4] = {bf2f(u[j].x), bf2f(u[j].y), bf2f(u[j].z), bf2f(u[j].w)};
#pragma unroll
            for (int q = 0; q < 4; ++q) {
                a0[q] += w[j].x * xv[q];
                a1[q] += w[j].y * xv[q];
                a2[q] += w[j].z * xv[q];
                a3[q] += w[j].w * xv[q];
            }
            ws0 += w[j].x; ws1 += w[j].y; ws2 += w[j].z; ws3 += w[j].w;
        }
    }
    for (; i < s1; i += 2) {
        int sn = sCSR[i];
        float4 w = *(const float4*)(wE + (size_t)i * 4);
        ushort4 u = *(const ushort4*)(xbf + (size_t)sn * 128 + fl);
        float xv[4] = {bf2f(u.x), bf2f(u.y), bf2f(u.z), bf2f(u.w)};
#pragma unroll
        for (int q = 0; q < 4; ++q) {
            a0[q] += w.x * xv[q];
            a1[q] += w.y * xv[q];
            a2[q] += w.z * xv[q];
            a3[q] += w.w * xv[q];
        }
        ws0 += w.x; ws1 += w.y; ws2 += w.z; ws3 += w.w;
    }
#pragma unroll
    for (int q = 0; q < 4; ++q) {
        a0[q] += __shfl_xor(a0[q], 32);
        a1[q] += __shfl_xor(a1[q], 32);
        a2[q] += __shfl_xor(a2[q], 32);
        a3[q] += __shfl_xor(a3[q], 32);
    }
    ws0 += __shfl_xor(ws0, 32); ws1 += __shfl_xor(ws1, 32);
    ws2 += __shfl_xor(ws2, 32); ws3 += __shfl_xor(ws3, 32);
    if (half == 0) {
        float i0 = 1.f / ws0, i1 = 1.f / ws1, i2 = 1.f / ws2, i3 = 1.f / ws3;
        int group = n >> 4, lrow = n & 15;
        int sl = fl >> 5;
        int kg = (fl >> 2) & 3;
        int j0 = ((fl >> 4) & 1) * 4;
        size_t base = ((size_t)group * 16 + sl) * 512 + (size_t)(kg * 16 + lrow) * 8 + j0;
        ushort4 o;
        o.x = f2bf(a0[0] * i0); o.y = f2bf(a0[1] * i0);
        o.z = f2bf(a0[2] * i0); o.w = f2bf(a0[3] * i0);
        *(ushort4*)(xaggF + base + 0 * 2048) = o;
        o.x = f2bf(a1[0] * i1); o.y = f2bf(a1[1] * i1);
        o.z = f2bf(a1[2] * i1); o.w = f2bf(a1[3] * i1);
        *(ushort4*)(xaggF + base + 1 * 2048) = o;
        o.x = f2bf(a2[0] * i2); o.y = f2bf(a2[1] * i2);
        o.z = f2bf(a2[2] * i2); o.w = f2bf(a2[3] * i2);
        *(ushort4*)(xaggF + base + 2 * 2048) = o;
        o.x = f2bf(a3[0] * i3); o.y = f2bf(a3[1] * i3);
        o.z = f2bf(a3[2] * i3); o.w = f2bf(a3[3] * i3);
        *(ushort4*)(xaggF + base + 3 * 2048) = o;
    }
}

// ---- layer-1 GEMM: out1F = elu(xaggF @ W1 + b1), fragment-native ----------
__global__ __launch_bounds__(64) void gemm1_mfma(const u16* __restrict__ xaggF,
                                                 const u16* __restrict__ W1f,
                                                 const float* __restrict__ b1,
                                                 u16* __restrict__ out1F) {
    int l = threadIdx.x;
    int head = blockIdx.y;
    int g0 = blockIdx.x * 2;
    int kg = l >> 4;

    bf16x8 xf[2][4];
#pragma unroll
    for (int g = 0; g < 2; ++g) {
        const u16* p = xaggF + ((size_t)(g0 + g) * 16 + head * 4) * 512 + l * 8;
#pragma unroll
        for (int s = 0; s < 4; ++s) xf[g][s] = *(const bf16x8*)(p + s * 512);
    }

    const u16* wbase = W1f + (size_t)head * 32 * 512 + l * 8;

#pragma unroll
    for (int cbp = 0; cbp < 4; ++cbp) {
        bf16x8 op0, op1;
#pragma unroll
        for (int par = 0; par < 2; ++par) {
            int cb = cbp * 2 + par;
            bf16x8 wf[4];
#pragma unroll
            for (int s = 0; s < 4; ++s)
                wf[s] = *(const bf16x8*)(wbase + (size_t)(cb * 4 + s) * 512);
            float4 bias = *(const float4*)(b1 + head * 128 + cb * 16 + kg * 4);
#pragma unroll
            for (int g = 0; g < 2; ++g) {
                f32x4 acc = {0.f, 0.f, 0.f, 0.f};
#pragma unroll
                for (int s = 0; s < 4; ++s)
                    acc = __builtin_amdgcn_mfma_f32_16x16x32_bf16(wf[s], xf[g][s],
                                                                  acc, 0, 0, 0);
                float v0 = ELU(acc[0] + bias.x);
                float v1 = ELU(acc[1] + bias.y);
                float v2 = ELU(acc[2] + bias.z);
                float v3 = ELU(acc[3] + bias.w);
                bf16x8& op = g ? op1 : op0;
                if (par == 0) {
                    op[0] = (short)f2bf(v0); op[1] = (short)f2bf(v1);
                    op[2] = (short)f2bf(v2); op[3] = (short)f2bf(v3);
                } else {
                    op[4] = (short)f2bf(v0); op[5] = (short)f2bf(v1);
                    op[6] = (short)f2bf(v2); op[7] = (short)f2bf(v3);
                }
            }
        }
#pragma unroll
        for (int g = 0; g < 2; ++g) {
            u16* op = out1F + ((size_t)(g0 + g) * 16 + head * 4 + cbp) * 512 + l * 8;
            *(bf16x8*)op = g ? op1 : op0;
        }
    }
}

// ---- layer-2 GEMM + fused al2, fragment-native ----------------------------
__global__ __launch_bounds__(64) void gemm2_mfma(const u16* __restrict__ out1F,
                                                 const u16* __restrict__ W2f,
                                                 const float* __restrict__ a_s2,
                                                 const float* __restrict__ a_d2,
                                                 u16* __restrict__ h2bf,
                                                 float* __restrict__ alS,
                                                 float* __restrict__ alD, int M) {
    int l = threadIdx.x;
    int g = blockIdx.x;
    int lrow = l & 15, kg = l >> 4;
    int node = g * 16 + lrow;

    const u16* xp = out1F + (size_t)g * 16 * 512 + l * 8;
    bf16x8 xf[16];
#pragma unroll
    for (int s = 0; s < 16; ++s) xf[s] = *(const bf16x8*)(xp + s * 512);

    const u16* wp = W2f + l * 8;
    float ps = 0.f, pd = 0.f;
#pragma unroll
    for (int c2 = 0; c2 < 4; ++c2) {
        int c0 = c2 * 16;
        f32x4 acc = {0.f, 0.f, 0.f, 0.f};
#pragma unroll
        for (int s = 0; s < 16; ++s) {
            bf16x8 wf = *(const bf16x8*)(wp + (size_t)(c2 * 16 + s) * 512);
            acc = __builtin_amdgcn_mfma_f32_16x16x32_bf16(wf, xf[s], acc, 0, 0, 0);
        }
        float4 as = *(const float4*)(a_s2 + c0 + kg * 4);
        float4 ad = *(const float4*)(a_d2 + c0 + kg * 4);
        ps += acc[0] * as.x + acc[1] * as.y + acc[2] * as.z + acc[3] * as.w;
        pd += acc[0] * ad.x + acc[1] * ad.y + acc[2] * ad.z + acc[3] * ad.w;
        if (node < M) {
            ushort4 o;
            o.x = f2bf(acc[0]); o.y = f2bf(acc[1]);
            o.z = f2bf(acc[2]); o.w = f2bf(acc[3]);
            *(ushort4*)(h2bf + (size_t)node * 64 + c0 + kg * 4) = o;
        }
    }
    ps += __shfl_xor(ps, 16); ps += __shfl_xor(ps, 32);
    pd += __shfl_xor(pd, 16); pd += __shfl_xor(pd, 32);
    if (kg == 0 && node < M) { alS[node] = ps; alD[node] = pd; }
}

// ---- layer-2 aggregate; weights inline (scalar); half-wave split ----------
__global__ __launch_bounds__(256) void agg2_kernel(const u16* __restrict__ h2bf,
                                                   const int* __restrict__ sCSR,
                                                   const int* __restrict__ offs,
                                                   const int* __restrict__ bsum,
                                                   const int* __restrict__ deg,
                                                   int NB,
                                                   const float* __restrict__ alS2,
                                                   const float* __restrict__ alD2,
                                                   const float* __restrict__ b2,
                                                   float* __restrict__ out2, int Nn) {
    int n = blockIdx.x * 4 + (threadIdx.x >> 6);
    int l = threadIdx.x & 63;
    int pref = bsum_pref(bsum, NB, (n < Nn ? n : 0) >> 11, l);
    if (n >= Nn) return;
    int half = l >> 5;
    int fl = (l & 31) * 2;        // feats fl, fl+1
    float ad = alD2[n];
    float ax = 0.f, ay = 0.f, ws = 0.f;
    int s0 = offs[n] + pref;
    int s1 = s0 + deg[n];
    int i = s0 + half;
    for (; i + 6 < s1; i += 8) {
        int sn[4]; float als[4]; u32 u[4];
#pragma unroll
        for (int j = 0; j < 4; ++j) sn[j] = sCSR[i + 2 * j];
#pragma unroll
        for (int j = 0; j < 4; ++j) {
            als[j] = alS2[sn[j]];
            u[j] = *(const u32*)(h2bf + (size_t)sn[j] * 64 + fl);
        }
#pragma unroll
        for (int j = 0; j < 4; ++j) {
            float t = als[j] + ad;
            float w = expf(LRELU(t));
            ax += w * __uint_as_float(u[j] << 16);
            ay += w * __uint_as_float(u[j] & 0xffff0000u);
            ws += w;
        }
    }
    for (; i < s1; i += 2) {
        int sn = sCSR[i];
        float t = alS2[sn] + ad;
        float w = expf(LRELU(t));
        u32 u = *(const u32*)(h2bf + (size_t)sn * 64 + fl);
        ax += w * __uint_as_float(u << 16);
        ay += w * __uint_as_float(u & 0xffff0000u);
        ws += w;
    }
    ax += __shfl_xor(ax, 32);
    ay += __shfl_xor(ay, 32);
    ws += __shfl_xor(ws, 32);
    if (half == 0) {
        float inv = 1.f / ws;
        float2 o;
        float v0 = ax * inv + b2[fl];
        float v1 = ay * inv + b2[fl + 1];
        o.x = ELU(v0);
        o.y = ELU(v1);
        *(float2*)(out2 + (size_t)n * 64 + fl) = o;
    }
}

// ---------------- fused pool + head (4 waves split the node loop) ----------
__device__ __forceinline__ int lower_bound_i(const int* arr, int n, int key) {
    int lo = 0, hi = n;
    while (lo < hi) {
        int mid = (lo + hi) >> 1;
        if (arr[mid] < key) lo = mid + 1; else hi = mid;
    }
    return lo;
}

__global__ __launch_bounds__(256) void poolfc_kernel(const float* __restrict__ h2,
                                                     const int* __restrict__ batch,
                                                     int Nn,
                                                     const float* __restrict__ w1,
                                                     const float* __restrict__ bb1,
                                                     const float* __restrict__ w2,
                                                     const float* __restrict__ bb2,
                                                     float* __restrict__ out) {
    int g = blockIdx.x;
    __shared__ int sh[2];
    __shared__ float psum[4][64];
    __shared__ float p[64];
    __shared__ float hid[32];
    int tid = threadIdx.x;
    int w = tid >> 6, t = tid & 63;
    if (tid == 0) sh[0] = lower_bound_i(batch, Nn, g);
    if (tid == 1) sh[1] = lower_bound_i(batch, Nn, g + 1);
    __syncthreads();
    int s0 = sh[0], s1 = sh[1];
    float sum = 0.f;
    for (int i = s0 + w; i < s1; i += 4) sum += h2[(size_t)i * 64 + t];
    psum[w][t] = sum;
    __syncthreads();
    if (w == 0) {
        float tot = psum[0][t] + psum[1][t] + psum[2][t] + psum[3][t];
        float cnt = (float)((s1 - s0) > 1 ? (s1 - s0) : 1);
        p[t] = tot / cnt;
    }
    __syncthreads();
    if (tid < 32) {
        float a = bb1[tid];
#pragma unroll
        for (int k = 0; k < 64; ++k) a += p[k] * w1[k * 32 + tid];
        hid[tid] = a > 0.f ? a : 0.f;
    }
    __syncthreads();
    if (tid == 0) {
        float a = bb2[0];
#pragma unroll
        for (int j = 0; j < 32; ++j) a += hid[j] * w2[j];
        out[g] = 1.0f / (1.0f + expf(-a));
    }
}

// ---------------------------------------------------------------------------
extern "C" void kernel_launch(void* const* d_in, const int* in_sizes, int n_in,
                              void* d_out, int out_size, void* d_ws, size_t ws_size,
                              hipStream_t stream) {
    const float* x      = (const float*)d_in[0];
    const int*   ei     = (const int*)d_in[1];
    const int*   batch  = (const int*)d_in[2];
    const float* W1     = (const float*)d_in[3];
    const float* a_src1 = (const float*)d_in[4];
    const float* a_dst1 = (const float*)d_in[5];
    const float* b1     = (const float*)d_in[6];
    const float* W2     = (const float*)d_in[7];
    const float* a_src2 = (const float*)d_in[8];
    const float* a_dst2 = (const float*)d_in[9];
    const float* b2     = (const float*)d_in[10];
    const float* fcw1   = (const float*)d_in[11];
    const float* fcb1   = (const float*)d_in[12];
    const float* fcw2   = (const float*)d_in[13];
    const float* fcb2   = (const float*)d_in[14];
    float* out = (float*)d_out;

    const int Nn = in_sizes[0] / 128;   // 25000
    const int E  = in_sizes[1] / 2;     // 400000
    const int Et = E + Nn;
    const int NG = out_size;            // 512
    const int* srcA = ei;
    const int* dstA = ei + E;

    const int ngroups = (Nn + 15) / 16;          // 1563
    const int ngp = (ngroups + 1) & ~1;          // padded even

    char* base = (char*)d_ws;
    size_t off = 0;
    auto alloc = [&](size_t bytes) -> void* {
        void* p = base + off;
        off += (bytes + 255) & ~(size_t)255;
        return p;
    };
    u16*   xbf    = (u16*)alloc((size_t)Nn * 128 * 2);
    u16*   xaggF  = (u16*)alloc((size_t)ngp * 16 * 512 * 2);   // B-frag order
    u16*   out1F  = (u16*)alloc((size_t)ngp * 16 * 512 * 2);   // B-frag order
    u16*   h2bf   = (u16*)alloc((size_t)Nn * 64 * 2);
    float* out2   = (float*)alloc((size_t)Nn * 64 * 4);
    u16*   W1f    = (u16*)alloc(65536 * 2);
    u16*   W2f    = (u16*)alloc(32768 * 2);
    float* Wa     = (float*)alloc(128 * 8 * 4);
    float* alS1   = (float*)alloc((size_t)Nn * 4 * 4);
    float* alD1   = (float*)alloc((size_t)Nn * 4 * 4);
    float* alS2   = (float*)alloc((size_t)Nn * 4);
    float* alD2   = (float*)alloc((size_t)Nn * 4);
    float* wE1    = (float*)alloc((size_t)Et * 4 * 4);
    int*   deg    = (int*)alloc((size_t)2 * Nn * 4);   // deg + fill contiguous
    int*   fill   = deg + Nn;
    int*   offs   = (int*)alloc((size_t)(Nn + 1) * 4);
    int*   bsum   = (int*)alloc(64 * 4);
    int*   sCSR   = (int*)alloc((size_t)Et * 4);
    (void)ws_size; (void)n_in;

    const int EB = (Et + 255) / 256;
    const int NB = (Nn + 2047) / 2048;              // scanA blocks (13)
    const int NBx = (Nn + 3) / 4;                   // prep_x node blocks
    const int ZB = (2 * Nn + 1023) / 1024;          // deg-zero blocks (49)

    // ---- 1: weight prep + Wa + zero deg/fill ----
    prep_w<<<388 + ZB, 256, 0, stream>>>(W1, W2, a_src1, a_dst1, W1f, W2f, Wa,
                                         deg, 2 * Nn);
    // ---- 2: x prep + al1 + degree count ----
    prep_x<<<NBx + EB, 256, 0, stream>>>(x, Wa, dstA, xbf, alS1, alD1, deg,
                                         Nn, E, NBx);
    // ---- 3-4: CSR build (partial scan; consumers fold the bsum prefix) ----
    scanA_kernel<<<NB, 256, 0, stream>>>(deg, offs, bsum, Nn);
    scatter_kernel<<<EB, 256, 0, stream>>>(srcA, dstA, E, Nn, offs, bsum, NB,
                                           fill, alS1, alD1, sCSR, wE1);

    // ---- 5-7: layer 1 + GEMMs ----
    aggx_kernel<<<(Nn + 3) / 4, 256, 0, stream>>>(xbf, sCSR, offs, bsum, deg, NB,
                                                  wE1, xaggF, Nn);
    dim3 g1(ngp / 2, 4);
    gemm1_mfma<<<g1, 64, 0, stream>>>(xaggF, W1f, b1, out1F);
    gemm2_mfma<<<ngroups, 64, 0, stream>>>(out1F, W2f, a_src2, a_dst2,
                                           h2bf, alS2, alD2, Nn);

    // ---- 8: layer-2 aggregate (weights inline, scalar) ----
    agg2_kernel<<<(Nn + 3) / 4, 256, 0, stream>>>(h2bf, sCSR, offs, bsum, deg, NB,
                                                  alS2, alD2, b2, out2, Nn);

    // ---- 9: fused pool + head ----
    poolfc_kernel<<<NG, 256, 0, stream>>>(out2, batch, Nn, fcw1, fcb1, fcw2,
                                          fcb2, out);
}